// Round 16
// baseline (243.437 us; speedup 1.0000x reference)
//
#include <hip/hip_runtime.h>
#include <hip/hip_cooperative_groups.h>

namespace cg = cooperative_groups;

// ---------------------------------------------------------------------------
// GCN 3-layer forward on a static graph.
// R2-R6: tiled SGEMM, parallel scan, int2 CSR, LDS histograms/rank-scatter.
// R7-R9: f32 SGEMM structurally capped ~45us (LDS pipe vs 4 SIMDs).
// R10: bf16 split-precision MFMA GEMM: 168->141.5us.
// R11: bf16 HT gather operand: ->124us (absmax 3e-5 -> 6.1e-5).
// R12: preprocessing occupancy (NB=256, u8 gpre, 2-stage norm): ->111.5us.
// R13: gemm reg-prefetch; ACT1 bf16; norm folded into csr_w: ->107.7us.
// R14: calibrated precision cuts: ->105.4us, absmax pinned 6.1e-5.
// R15: coop preproc fusion FAILED: 296-block cooperative launch silently
//     rejected (output=zeros => preproc never ran). Suspect grid > max
//     co-resident (driver gave 1 blk/CU, 256 max < 296).
// R16: grid = 256 EXACTLY (= CU count, safe at 1 blk/CU). wsplit folded into
//     P0 via global index j = b*1024+t < 40960 (blocks 0..39).
// ---------------------------------------------------------------------------

#define NB 256     // edge groups == hist/scatter blocks == coop grid
#define NW4 8192   // N/4 packed words (N = 32768)
#define RSEG 8     // r-segments for the 2-stage partials reduction

typedef unsigned int uint32;
typedef unsigned char uchar_t;
typedef unsigned short ushort_t;
typedef __attribute__((ext_vector_type(8))) short bf16x8;
typedef __attribute__((ext_vector_type(4))) float f32x4;

__device__ inline ushort_t f2bf(float f) {
  uint32 u = __float_as_uint(f);
  u += 0x7fffu + ((u >> 16) & 1u);
  return (ushort_t)(u >> 16);
}
__device__ inline float bf2f(ushort_t h) { return __uint_as_float(((uint32)h) << 16); }

// tanh = (e^{2x}-1)/(e^{2x}+1)
__device__ inline float fast_tanh(float x) {
  float xc = fminf(fmaxf(x, -30.f), 30.f);
  float t = __expf(2.0f * xc);
  return (t - 1.0f) * __builtin_amdgcn_rcpf(t + 1.0f);
}

// ---------------------------------------------------------------------------
// Cooperative preprocessing: 256 blocks x 1024 threads (1 blk/CU guaranteed).
// P0 hist + wsplit(j<40960) -> P1 psum -> P2 norms+chunk sums ->
// P3 scan+row_ptr+gpre -> P4 rank-scatter. grid.sync between phases.
// ---------------------------------------------------------------------------
__global__ __launch_bounds__(1024, 8) void preproc_coop(
    const int* __restrict__ src, const int* __restrict__ dst, const float* __restrict__ ew,
    const float* __restrict__ W1, const float* __restrict__ W2,
    ushort_t* __restrict__ WhT1, ushort_t* __restrict__ WlT1, ushort_t* __restrict__ WhT2,
    uint32* __restrict__ part, uint32* __restrict__ psum,
    float* __restrict__ norm_src, float* __restrict__ norm_dst, int* __restrict__ in_deg,
    int* __restrict__ block_sums, int* __restrict__ row_ptr, uchar_t* __restrict__ gpre,
    int2* __restrict__ csr, int n, int e, int epb) {
  cg::grid_group grid = cg::this_grid();
  __shared__ uint32 hs[NW4]; // 32KB: hist(src) / P3 scratch / P4 rank hist
  __shared__ uint32 hd[NW4]; // 32KB: hist(dst)
  const int t = threadIdx.x;
  const int b = blockIdx.x;
  const int n4 = n >> 2;

  // ---- P0: per-block histograms; blocks 0..39 also W pre-split ----
  for (int w = t; w < NW4; w += 1024) {
    hs[w] = 0;
    hd[w] = 0;
  }
  __syncthreads();
  {
    const int base = b * epb;
    for (int k = t; k < epb; k += 1024) {
      int i = base + k;
      if (i < e) {
        int s = src[i], d = dst[i];
        atomicAdd(&hs[s >> 2], 1u << ((s & 3) * 8));
        atomicAdd(&hd[d >> 2], 1u << ((d & 3) * 8));
      }
    }
    __syncthreads();
    uint32* ps = part + (size_t)b * NW4;
    uint32* pd = part + (size_t)(NB + b) * NW4;
    for (int w = t; w < NW4; w += 1024) {
      ps[w] = hs[w];
      pd[w] = hd[w];
    }
    // W pre-split, distributed over the whole grid (j < 256*128 + 128*64)
    int j = b * 1024 + t;
    if (j < 256 * 128) {
      int k = j / 128, c = j % 128;
      float f = W1[j];
      ushort_t h = f2bf(f);
      WhT1[(size_t)c * 256 + k] = h;
      WlT1[(size_t)c * 256 + k] = f2bf(f - bf2f(h));
    } else if (j < 256 * 128 + 128 * 64) {
      int jj = j - 256 * 128;
      int k = jj / 64, c = jj % 64;
      WhT2[(size_t)c * 128 + k] = f2bf(W2[jj]);
    }
  }
  grid.sync();

  // ---- P1: psum[a][seg][w] = sum of NB/RSEG partials ----
  {
    int task = b * 1024 + t;
    const int ntask = 2 * RSEG * n4; // 131072
    if (task < ntask) {
      int a = task / (RSEG * n4);
      int rem = task % (RSEG * n4);
      int seg = rem / n4;
      int w = rem % n4;
      const uint32* p = part + (size_t)a * NB * n4 + (size_t)seg * (NB / RSEG) * n4 + w;
      uint32 s = 0;
#pragma unroll
      for (int r = 0; r < NB / RSEG; ++r) s += p[(size_t)r * n4];
      psum[task] = s;
    }
  }
  grid.sync();

  // ---- P2: fold segments -> norms/in_deg + per-256-node chunk sums ----
  if (b < 32 && t < 256) {
    int w = b * 256 + t;
    uint32 ss = 0, sd = 0;
#pragma unroll
    for (int seg = 0; seg < RSEG; ++seg) {
      ss += psum[(size_t)seg * n4 + w];
      sd += psum[(size_t)(RSEG + seg) * n4 + w];
    }
    int idsum = 0;
#pragma unroll
    for (int j = 0; j < 4; ++j) {
      int v = w * 4 + j;
      int od = (ss >> (j * 8)) & 0xff;
      int id = (sd >> (j * 8)) & 0xff;
      norm_src[v] = 1.0f / sqrtf((float)max(od, 1));
      norm_dst[v] = 1.0f / sqrtf((float)max(id, 1));
      in_deg[v] = id;
      idsum += id;
    }
#pragma unroll
    for (int off = 32; off > 0; off >>= 1) idsum += __shfl_down(idsum, off, 64);
    if ((t & 63) == 0) block_sums[w >> 6] = idsum;
  }
  grid.sync();

  // ---- P3: chunk scan -> row_ptr + u8 group offsets (blocks 0..127) ----
  {
    int* sh = (int*)hs;
    const bool act = (b < 128);
    const int gid = b * 256 + (t & 255);
    // exclusive block offset = sum block_sums[0..b)
    int v = (act && t < b && t < 128) ? block_sums[t] : 0;
#pragma unroll
    for (int off = 32; off > 0; off >>= 1) v += __shfl_down(v, off, 64);
    if ((t & 63) == 0) sh[512 + (t >> 6)] = v;
    __syncthreads();
    const int s_boff = sh[512] + sh[513]; // only waves 0,1 carry t<128 terms
    __syncthreads();
    int d = (act && t < 256 && gid < n) ? in_deg[gid] : 0;
    if (t < 256) sh[t] = d;
    __syncthreads();
    for (int off = 1; off < 256; off <<= 1) {
      int vv = 0, add = 0;
      if (t < 256) {
        vv = sh[t];
        add = (t >= off) ? sh[t - off] : 0;
      }
      __syncthreads();
      if (t < 256) sh[t] = vv + add;
      __syncthreads();
    }
    if (act && t < 256 && gid < n) {
      int excl = s_boff + sh[t] - d;
      row_ptr[gid] = excl;
      if (gid == n - 1) row_ptr[n] = excl + d;
      const int w = gid >> 2;
      const int shft = (gid & 3) * 8;
      int cum = 0;
#pragma unroll 8
      for (int r = 0; r < NB; ++r) {
        gpre[(size_t)r * n + gid] = (uchar_t)cum;
        cum += (part[(size_t)(NB + r) * n4 + w] >> shft) & 0xff;
      }
    }
  }
  grid.sync();

  // ---- P4: rank-scatter, csr_w = ew * norm_src[src] ----
  {
    for (int w = t; w < NW4; w += 1024) hs[w] = 0;
    __syncthreads();
    const int base = b * epb;
    const uchar_t* gp = gpre + (size_t)b * n;
    for (int k = t; k < epb; k += 1024) {
      int i = base + k;
      if (i < e) {
        int s = src[i];
        int d = dst[i];
        uint32 sh2 = (d & 3) * 8;
        uint32 old = atomicAdd(&hs[d >> 2], 1u << sh2);
        int rank = (old >> sh2) & 0xff;
        int pos = row_ptr[d] + (int)gp[d] + rank;
        csr[pos] = make_int2(s, __float_as_int(ew[i] * norm_src[s]));
      }
    }
  }
}

// ---------------------------------------------------------------------------
// MFMA GEMM, f32 input rounded to bf16-high: ht = bf16(x @ W), 2 MFMAs.
// ---------------------------------------------------------------------------
template <int K, int OUT>
__global__ __launch_bounds__(256) void gemm_mfma(const float* __restrict__ x,
                                                 const ushort_t* __restrict__ WhT,
                                                 const ushort_t* __restrict__ WlT,
                                                 ushort_t* __restrict__ ht, int n) {
  constexpr int BK = 64, KP = BK + 8;
  constexpr int NCT = OUT / 32;
  constexpr int NWLD = OUT * 16 / 256;
  __shared__ ushort_t Xh[64][KP];
  __shared__ ushort_t Wh[OUT][KP], Wl[OUT][KP];

  const int tid = threadIdx.x;
  const int wv = tid >> 6;
  const int lane = tid & 63;
  const int wr = wv >> 1;
  const int wc = wv & 1;
  const int row0 = blockIdx.x * 64;
  const int fr = lane & 15;
  const int fg = lane >> 4;

  f32x4 acc[2][NCT];
#pragma unroll
  for (int i = 0; i < 2; ++i)
#pragma unroll
    for (int j = 0; j < NCT; ++j) acc[i][j] = (f32x4){0.f, 0.f, 0.f, 0.f};

  float4 xr[4];
  ushort4 wrh[NWLD], wrl[NWLD];

#define LOADX(kg)                                                                       \
  {                                                                                     \
    _Pragma("unroll") for (int p_ = 0; p_ < 4; ++p_) {                                  \
      int idx_ = p_ * 256 + tid;                                                        \
      xr[p_] = *reinterpret_cast<const float4*>(                                        \
          x + (size_t)(row0 + (idx_ >> 4)) * K + (kg) + (idx_ & 15) * 4);               \
    }                                                                                   \
  }
#define LOADW(kg)                                                                       \
  {                                                                                     \
    _Pragma("unroll") for (int p_ = 0; p_ < NWLD; ++p_) {                               \
      int idx_ = p_ * 256 + tid;                                                        \
      int c_ = idx_ >> 4, k4_ = idx_ & 15;                                              \
      wrh[p_] = *reinterpret_cast<const ushort4*>(WhT + (size_t)c_ * K + (kg) + k4_ * 4);\
      wrl[p_] = *reinterpret_cast<const ushort4*>(WlT + (size_t)c_ * K + (kg) + k4_ * 4);\
    }                                                                                   \
  }

  LOADX(0);
  LOADW(0);

#pragma unroll 1
  for (int k0 = 0; k0 < K; k0 += BK) {
    __syncthreads();
#pragma unroll
    for (int p = 0; p < 4; ++p) {
      int idx = p * 256 + tid;
      int r = idx >> 4, c4 = idx & 15;
      float4 v = xr[p];
      ushort4 h;
      h.x = f2bf(v.x);
      h.y = f2bf(v.y);
      h.z = f2bf(v.z);
      h.w = f2bf(v.w);
      *reinterpret_cast<ushort4*>(&Xh[r][c4 * 4]) = h;
    }
#pragma unroll
    for (int p = 0; p < NWLD; ++p) {
      int idx = p * 256 + tid;
      int c = idx >> 4, k4 = idx & 15;
      *reinterpret_cast<ushort4*>(&Wh[c][k4 * 4]) = wrh[p];
      *reinterpret_cast<ushort4*>(&Wl[c][k4 * 4]) = wrl[p];
    }
    if (k0 + BK < K) {
      LOADX(k0 + BK);
      LOADW(k0 + BK);
    }
    __syncthreads();

#pragma unroll
    for (int s = 0; s < 2; ++s) {
      const int kk = s * 32 + fg * 8;
      bf16x8 ah[2];
#pragma unroll
      for (int i = 0; i < 2; ++i)
        ah[i] = *reinterpret_cast<const bf16x8*>(&Xh[wr * 32 + i * 16 + fr][kk]);
#pragma unroll
      for (int j = 0; j < NCT; ++j) {
        int c = wc * (OUT / 2) + j * 16 + fr;
        bf16x8 bh = *reinterpret_cast<const bf16x8*>(&Wh[c][kk]);
        bf16x8 bl = *reinterpret_cast<const bf16x8*>(&Wl[c][kk]);
#pragma unroll
        for (int i = 0; i < 2; ++i) {
          acc[i][j] = __builtin_amdgcn_mfma_f32_16x16x32_bf16(ah[i], bh, acc[i][j], 0, 0, 0);
          acc[i][j] = __builtin_amdgcn_mfma_f32_16x16x32_bf16(ah[i], bl, acc[i][j], 0, 0, 0);
        }
      }
    }
  }
#undef LOADX
#undef LOADW

#pragma unroll
  for (int i = 0; i < 2; ++i) {
#pragma unroll
    for (int q = 0; q < 4; ++q) {
      int row = row0 + wr * 32 + i * 16 + fg * 4 + q;
#pragma unroll
      for (int j = 0; j < NCT; ++j) {
        int col = wc * (OUT / 2) + j * 16 + fr;
        ht[(size_t)row * OUT + col] = f2bf(acc[i][j][q]);
      }
    }
  }
}

// ---------------------------------------------------------------------------
// bf16-input MFMA GEMM, W bf16-high only: 1 MFMA per fragment.
// ---------------------------------------------------------------------------
template <int K, int OUT>
__global__ __launch_bounds__(256) void gemm_mfma_bf16in(const ushort_t* __restrict__ x,
                                                        const ushort_t* __restrict__ WhT,
                                                        ushort_t* __restrict__ ht, int n) {
  constexpr int BK = 64, KP = BK + 8;
  constexpr int NCT = OUT / 32;
  constexpr int NWLD = OUT * 16 / 256;
  __shared__ ushort_t Xh[64][KP];
  __shared__ ushort_t Wh[OUT][KP];

  const int tid = threadIdx.x;
  const int wv = tid >> 6;
  const int lane = tid & 63;
  const int wr = wv >> 1;
  const int wc = wv & 1;
  const int row0 = blockIdx.x * 64;
  const int fr = lane & 15;
  const int fg = lane >> 4;

  f32x4 acc[2][NCT];
#pragma unroll
  for (int i = 0; i < 2; ++i)
#pragma unroll
    for (int j = 0; j < NCT; ++j) acc[i][j] = (f32x4){0.f, 0.f, 0.f, 0.f};

  ushort4 xr[4];
  ushort4 wrh[NWLD];

#define LOADX(kg)                                                                       \
  {                                                                                     \
    _Pragma("unroll") for (int p_ = 0; p_ < 4; ++p_) {                                  \
      int idx_ = p_ * 256 + tid;                                                        \
      xr[p_] = *reinterpret_cast<const ushort4*>(                                       \
          x + (size_t)(row0 + (idx_ >> 4)) * K + (kg) + (idx_ & 15) * 4);               \
    }                                                                                   \
  }
#define LOADW(kg)                                                                       \
  {                                                                                     \
    _Pragma("unroll") for (int p_ = 0; p_ < NWLD; ++p_) {                               \
      int idx_ = p_ * 256 + tid;                                                        \
      int c_ = idx_ >> 4, k4_ = idx_ & 15;                                              \
      wrh[p_] = *reinterpret_cast<const ushort4*>(WhT + (size_t)c_ * K + (kg) + k4_ * 4);\
    }                                                                                   \
  }

  LOADX(0);
  LOADW(0);

#pragma unroll 1
  for (int k0 = 0; k0 < K; k0 += BK) {
    __syncthreads();
#pragma unroll
    for (int p = 0; p < 4; ++p) {
      int idx = p * 256 + tid;
      *reinterpret_cast<ushort4*>(&Xh[idx >> 4][(idx & 15) * 4]) = xr[p];
    }
#pragma unroll
    for (int p = 0; p < NWLD; ++p) {
      int idx = p * 256 + tid;
      *reinterpret_cast<ushort4*>(&Wh[idx >> 4][(idx & 15) * 4]) = wrh[p];
    }
    if (k0 + BK < K) {
      LOADX(k0 + BK);
      LOADW(k0 + BK);
    }
    __syncthreads();

#pragma unroll
    for (int s = 0; s < 2; ++s) {
      const int kk = s * 32 + fg * 8;
      bf16x8 ah[2];
#pragma unroll
      for (int i = 0; i < 2; ++i)
        ah[i] = *reinterpret_cast<const bf16x8*>(&Xh[wr * 32 + i * 16 + fr][kk]);
#pragma unroll
      for (int j = 0; j < NCT; ++j) {
        int c = wc * (OUT / 2) + j * 16 + fr;
        bf16x8 bh = *reinterpret_cast<const bf16x8*>(&Wh[c][kk]);
#pragma unroll
        for (int i = 0; i < 2; ++i)
          acc[i][j] = __builtin_amdgcn_mfma_f32_16x16x32_bf16(ah[i], bh, acc[i][j], 0, 0, 0);
      }
    }
  }
#undef LOADX
#undef LOADW

#pragma unroll
  for (int i = 0; i < 2; ++i) {
#pragma unroll
    for (int q = 0; q < 4; ++q) {
      int row = row0 + wr * 32 + i * 16 + fg * 4 + q;
#pragma unroll
      for (int j = 0; j < NCT; ++j) {
        int col = wc * (OUT / 2) + j * 16 + fr;
        ht[(size_t)row * OUT + col] = f2bf(acc[i][j][q]);
      }
    }
  }
}

// bf16 gather: 4 bf16 (8B) per lane-group slot
#define GATHB(e, acc)                                                               \
  {                                                                                 \
    float w_ = __int_as_float(e.y);                                                 \
    ushort4 h_ = *reinterpret_cast<const ushort4*>(ht + (size_t)e.x * OUT + cg * 4);\
    acc.x += w_ * bf2f(h_.x);                                                       \
    acc.y += w_ * bf2f(h_.y);                                                       \
    acc.z += w_ * bf2f(h_.z);                                                       \
    acc.w += w_ * bf2f(h_.w);                                                       \
  }

// out[v] = tanh(nd*sum + b), written bf16
template <int OUT>
__global__ void aggregate_kernel(const ushort_t* __restrict__ ht, const int* __restrict__ row_ptr,
                                 const int2* __restrict__ csr, const float* __restrict__ norm_dst,
                                 const float* __restrict__ bias, ushort_t* __restrict__ out,
                                 int n) {
  constexpr int LPN = OUT / 4;
  constexpr int NPB = 256 / LPN;
  const int tid = threadIdx.x;
  const int cg = tid % LPN;
  const int v = blockIdx.x * NPB + tid / LPN;
  if (v >= n) return;

  const int s0 = row_ptr[v];
  const int s1 = row_ptr[v + 1];
  float4 a0 = {0, 0, 0, 0}, a1 = {0, 0, 0, 0}, a2 = {0, 0, 0, 0}, a3 = {0, 0, 0, 0};
  int i = s0;
  for (; i + 4 <= s1; i += 4) {
    int2 e0 = csr[i], e1 = csr[i + 1], e2 = csr[i + 2], e3 = csr[i + 3];
    GATHB(e0, a0);
    GATHB(e1, a1);
    GATHB(e2, a2);
    GATHB(e3, a3);
  }
  for (; i < s1; ++i) {
    int2 e = csr[i];
    GATHB(e, a0);
  }
  float nd = norm_dst[v];
  float4 b4 = *reinterpret_cast<const float4*>(bias + cg * 4);
  ushort4 r;
  r.x = f2bf(fast_tanh((a0.x + a1.x + a2.x + a3.x) * nd + b4.x));
  r.y = f2bf(fast_tanh((a0.y + a1.y + a2.y + a3.y) * nd + b4.y));
  r.z = f2bf(fast_tanh((a0.z + a1.z + a2.z + a3.z) * nd + b4.z));
  r.w = f2bf(fast_tanh((a0.w + a1.w + a2.w + a3.w) * nd + b4.w));
  *reinterpret_cast<ushort4*>(out + (size_t)v * OUT + cg * 4) = r;
}

// Layer-2 aggregate fused with layer-3 transform (norm folded into csr_w).
__global__ void aggregate2_fuse3(const ushort_t* __restrict__ ht, const int* __restrict__ row_ptr,
                                 const int2* __restrict__ csr, const float* __restrict__ norm_dst,
                                 const float* __restrict__ bias, const float* __restrict__ W3,
                                 float* __restrict__ ht3, int n) {
  constexpr int OUT = 64;
  constexpr int LPN = OUT / 4; // 16
  constexpr int NPB = 256 / LPN;
  const int tid = threadIdx.x;
  const int cg = tid % LPN;
  const int v = blockIdx.x * NPB + tid / LPN;
  if (v >= n) return;

  const int s0 = row_ptr[v];
  const int s1 = row_ptr[v + 1];
  float4 a0 = {0, 0, 0, 0}, a1 = {0, 0, 0, 0}, a2 = {0, 0, 0, 0}, a3 = {0, 0, 0, 0};
  int i = s0;
  for (; i + 4 <= s1; i += 4) {
    int2 e0 = csr[i], e1 = csr[i + 1], e2 = csr[i + 2], e3 = csr[i + 3];
    GATHB(e0, a0);
    GATHB(e1, a1);
    GATHB(e2, a2);
    GATHB(e3, a3);
  }
  for (; i < s1; ++i) {
    int2 e = csr[i];
    GATHB(e, a0);
  }
  float nd = norm_dst[v];
  float4 b4 = *reinterpret_cast<const float4*>(bias + cg * 4);
  float ox = fast_tanh((a0.x + a1.x + a2.x + a3.x) * nd + b4.x);
  float oy = fast_tanh((a0.y + a1.y + a2.y + a3.y) * nd + b4.y);
  float oz = fast_tanh((a0.z + a1.z + a2.z + a3.z) * nd + b4.z);
  float ow = fast_tanh((a0.w + a1.w + a2.w + a3.w) * nd + b4.w);
  float4 w3 = *reinterpret_cast<const float4*>(W3 + cg * 4);
  float p = ox * w3.x + oy * w3.y + oz * w3.z + ow * w3.w;
#pragma unroll
  for (int m = 1; m < 16; m <<= 1) p += __shfl_xor(p, m, 64);
  if (cg == 0) ht3[v] = p;
}

__global__ void aggregate3_kernel(const float* __restrict__ ht3, const int* __restrict__ row_ptr,
                                  const int2* __restrict__ csr, const float* __restrict__ norm_dst,
                                  const float* __restrict__ b3, float* __restrict__ out, int n) {
  int v = blockIdx.x * blockDim.x + threadIdx.x;
  if (v >= n) return;
  const int s0 = row_ptr[v];
  const int s1 = row_ptr[v + 1];
  float p0 = 0.f, p1 = 0.f, p2 = 0.f, p3 = 0.f;
  int i = s0;
  for (; i + 4 <= s1; i += 4) {
    int2 e0 = csr[i], e1 = csr[i + 1], e2 = csr[i + 2], e3 = csr[i + 3];
    p0 += __int_as_float(e0.y) * ht3[e0.x];
    p1 += __int_as_float(e1.y) * ht3[e1.x];
    p2 += __int_as_float(e2.y) * ht3[e2.x];
    p3 += __int_as_float(e3.y) * ht3[e3.x];
  }
  for (; i < s1; ++i) {
    int2 e = csr[i];
    p0 += __int_as_float(e.y) * ht3[e.x];
  }
  out[v] = (p0 + p1 + p2 + p3) * norm_dst[v] + b3[0];
}

extern "C" void kernel_launch(void* const* d_in, const int* in_sizes, int n_in,
                              void* d_out, int out_size, void* d_ws, size_t ws_size,
                              hipStream_t stream) {
  const float* b_z = (const float*)d_in[0];
  const int* src = (const int*)d_in[1];
  const int* dst = (const int*)d_in[2];
  const float* ew = (const float*)d_in[3];
  const float* W1 = (const float*)d_in[4];
  const float* b1 = (const float*)d_in[5];
  const float* W2 = (const float*)d_in[6];
  const float* b2 = (const float*)d_in[7];
  const float* W3 = (const float*)d_in[8];
  const float* b3 = (const float*)d_in[9];

  const int N = in_sizes[0] / 256; // 32768
  const int E = in_sizes[1];       // 524288
  const int N4 = N / 4;            // 8192
  const int epb = (E + NB - 1) / NB; // 2048

  char* ws = (char*)d_ws;
  size_t off = 0;
  auto alloc = [&](size_t bytes) -> void* {
    void* p = ws + off;
    off += (bytes + 255) & ~(size_t)255;
    return p;
  };

  uint32* part = (uint32*)alloc((size_t)2 * NB * N4 * 4);   // 16 MB
  uint32* psum = (uint32*)alloc((size_t)2 * RSEG * N4 * 4); // 512 KB
  uchar_t* gpre = (uchar_t*)alloc((size_t)NB * N);          // 8 MB
  float* norm_src = (float*)alloc((size_t)N * 4);
  float* norm_dst = (float*)alloc((size_t)N * 4);
  int* in_deg = (int*)alloc((size_t)N * 4);
  int* row_ptr = (int*)alloc((size_t)(N + 1) * 4);
  int* block_sums = (int*)alloc(256 * 4);
  int2* csr = (int2*)alloc((size_t)E * 8);
  ushort_t* HT = (ushort_t*)alloc((size_t)N * 128 * 2);   // bf16 ht1 / ht2 (reused)
  ushort_t* ACT1 = (ushort_t*)alloc((size_t)N * 128 * 2); // bf16 layer1 activation
  float* HT3 = (float*)alloc((size_t)N * 4);
  ushort_t* WhT1 = (ushort_t*)alloc((size_t)256 * 128 * 2);
  ushort_t* WlT1 = (ushort_t*)alloc((size_t)256 * 128 * 2);
  ushort_t* WhT2 = (ushort_t*)alloc((size_t)128 * 64 * 2);

  const int nBlocks = (N + 255) / 256; // 128

  int n_arg = N, e_arg = E, epb_arg = epb;
  void* cargs[] = {(void*)&src,      (void*)&dst,        (void*)&ew,       (void*)&W1,
                   (void*)&W2,       (void*)&WhT1,       (void*)&WlT1,     (void*)&WhT2,
                   (void*)&part,     (void*)&psum,       (void*)&norm_src, (void*)&norm_dst,
                   (void*)&in_deg,   (void*)&block_sums, (void*)&row_ptr,  (void*)&gpre,
                   (void*)&csr,      (void*)&n_arg,      (void*)&e_arg,    (void*)&epb_arg};
  hipLaunchCooperativeKernel((void*)preproc_coop, dim3(NB), dim3(1024), cargs, 0, stream);

  // Layer 1: 256 -> 128, tanh (output bf16)
  gemm_mfma<256, 128><<<N / 64, 256, 0, stream>>>(b_z, WhT1, WlT1, HT, N);
  aggregate_kernel<128><<<(N + 7) / 8, 256, 0, stream>>>(HT, row_ptr, csr, norm_dst, b1, ACT1, N);
  // Layer 2: 128 -> 64 (tanh) fused with layer-3 transform (64 -> 1)
  gemm_mfma_bf16in<128, 64><<<N / 64, 256, 0, stream>>>(ACT1, WhT2, HT, N);
  aggregate2_fuse3<<<(N + 15) / 16, 256, 0, stream>>>(HT, row_ptr, csr, norm_dst, b2, W3, HT3, N);
  // Layer 3 aggregate: 1 col, no tanh
  aggregate3_kernel<<<nBlocks, 256, 0, stream>>>(HT3, row_ptr, csr, norm_dst, b3,
                                                 (float*)d_out, N);
}

// Round 17
// 108.126 us; speedup vs baseline: 2.2514x; 2.2514x over previous
//
#include <hip/hip_runtime.h>

// ---------------------------------------------------------------------------
// GCN 3-layer forward on a static graph.
// R2-R6: tiled SGEMM, parallel scan, int2 CSR, LDS histograms/rank-scatter.
// R7-R9: f32 SGEMM structurally capped ~45us (LDS pipe vs 4 SIMDs).
// R10: bf16 split-precision MFMA GEMM: 168->141.5us.
// R11: bf16 HT gather operand: ->124us (absmax 3e-5 -> 6.1e-5).
// R12: preprocessing occupancy (NB=256, u8 gpre, 2-stage norm): ->111.5us.
// R13: gemm reg-prefetch; ACT1 bf16; norm folded into csr_w: ->107.7us.
// R14: calibrated precision cuts: ->105.4us, absmax pinned 6.1e-5.
// R15/R16: cooperative preproc fusion -- R15 launch rejected (grid 296 > max
//     co-resident); R16 at grid 256 RAN but grid.sync costs ~35us each
//     (system-scope spin across 8 non-coherent XCD L2s): 164us alone. DEAD.
//     Side-finding: R14 preproc section is only ~26us -> launch gaps smaller
//     than modeled; budget is mostly real kernel work.
// R17: revert to R14 + fuse norm_partial/norm_final into one norm_reduce
//     (4 threads/word x 64-partial serial sums + shfl; dst blocks emit chunk
//     sums via LDS). 10 -> 9 launches, psum buffer gone.
// ---------------------------------------------------------------------------

#define NB 256     // edge groups == hist/scatter blocks
#define NW4 8192   // N/4 packed words (N = 32768)

typedef unsigned int uint32;
typedef unsigned char uchar_t;
typedef unsigned short ushort_t;
typedef __attribute__((ext_vector_type(8))) short bf16x8;
typedef __attribute__((ext_vector_type(4))) float f32x4;

__device__ inline ushort_t f2bf(float f) {
  uint32 u = __float_as_uint(f);
  u += 0x7fffu + ((u >> 16) & 1u);
  return (ushort_t)(u >> 16);
}
__device__ inline float bf2f(ushort_t h) { return __uint_as_float(((uint32)h) << 16); }

// tanh = (e^{2x}-1)/(e^{2x}+1)
__device__ inline float fast_tanh(float x) {
  float xc = fminf(fmaxf(x, -30.f), 30.f);
  float t = __expf(2.0f * xc);
  return (t - 1.0f) * __builtin_amdgcn_rcpf(t + 1.0f);
}

// --- hist (blocks < NB) + W pre-split (blocks >= NB) ------------------------
__global__ __launch_bounds__(1024) void hist_wsplit_kernel(
    const int* __restrict__ src, const int* __restrict__ dst, uint32* __restrict__ part,
    const float* __restrict__ W1, const float* __restrict__ W2,
    ushort_t* __restrict__ WhT1, ushort_t* __restrict__ WlT1,
    ushort_t* __restrict__ WhT2, int e, int epb) {
  const int t = threadIdx.x;
  if (blockIdx.x >= NB) {
    int i = (blockIdx.x - NB) * 1024 + t;
    if (i < 256 * 128) {
      int k = i / 128, c = i % 128;
      float f = W1[i];
      ushort_t h = f2bf(f);
      WhT1[(size_t)c * 256 + k] = h;
      WlT1[(size_t)c * 256 + k] = f2bf(f - bf2f(h));
    } else if (i < 256 * 128 + 128 * 64) {
      int j = i - 256 * 128;
      int k = j / 64, c = j % 64;
      WhT2[(size_t)c * 128 + k] = f2bf(W2[j]);
    }
    return;
  }
  __shared__ uint32 hs[NW4];
  __shared__ uint32 hd[NW4];
  for (int w = t; w < NW4; w += 1024) {
    hs[w] = 0;
    hd[w] = 0;
  }
  __syncthreads();
  const int base = blockIdx.x * epb;
  for (int k = t; k < epb; k += 1024) {
    int i = base + k;
    if (i < e) {
      int s = src[i], d = dst[i];
      atomicAdd(&hs[s >> 2], 1u << ((s & 3) * 8));
      atomicAdd(&hd[d >> 2], 1u << ((d & 3) * 8));
    }
  }
  __syncthreads();
  uint32* ps = part + (size_t)blockIdx.x * NW4;
  uint32* pd = part + (size_t)(NB + blockIdx.x) * NW4;
  for (int w = t; w < NW4; w += 1024) {
    ps[w] = hs[w];
    pd[w] = hd[w];
  }
}

// --- fused norm reduce: 64 blocks x 1024; 4 threads per packed word ---------
// pair < n4: src sums -> norm_src; pair >= n4: dst sums -> norm_dst, in_deg,
// and per-256-node chunk sums (blocks 32..63 each own 4 chunks).
__global__ __launch_bounds__(1024) void norm_reduce(const uint32* __restrict__ part,
                                                    float* __restrict__ norm_src,
                                                    float* __restrict__ norm_dst,
                                                    int* __restrict__ in_deg,
                                                    int* __restrict__ block_sums, int n4) {
  __shared__ int chunk[4];
  const int t = threadIdx.x;
  if (t < 4) chunk[t] = 0;
  __syncthreads();
  const int tid = blockIdx.x * 1024 + t;
  const int pair = tid >> 2;
  const int sub = tid & 3;
  const int a = (pair >= n4) ? 1 : 0;
  const int w = pair - a * n4;
  const uint32* p = part + (size_t)a * NB * n4 + (size_t)sub * (NB / 4) * n4 + w;
  uint32 s = 0;
#pragma unroll
  for (int r = 0; r < NB / 4; ++r) s += p[(size_t)r * n4];
  s += __shfl_down(s, 1, 64);
  s += __shfl_down(s, 2, 64);
  if (sub == 0) {
    if (a == 0) {
#pragma unroll
      for (int j = 0; j < 4; ++j) {
        int od = (s >> (j * 8)) & 0xff;
        norm_src[w * 4 + j] = 1.0f / sqrtf((float)max(od, 1));
      }
    } else {
      int idsum = 0;
#pragma unroll
      for (int j = 0; j < 4; ++j) {
        int id = (s >> (j * 8)) & 0xff;
        norm_dst[w * 4 + j] = 1.0f / sqrtf((float)max(id, 1));
        in_deg[w * 4 + j] = id;
        idsum += id;
      }
      atomicAdd(&chunk[(w >> 6) & 3], idsum);
    }
  }
  __syncthreads();
  if (blockIdx.x >= 32 && t < 4) block_sums[(blockIdx.x - 32) * 4 + t] = chunk[t];
}

// --- chunk scan (block offset inlined) -> row_ptr + u8 group offsets --------
__global__ __launch_bounds__(256) void scan_write_goffs(const int* __restrict__ in_deg,
                                                        const int* __restrict__ block_sums,
                                                        const uint32* __restrict__ part_dst,
                                                        int* __restrict__ row_ptr,
                                                        uchar_t* __restrict__ gpre, int n) {
  __shared__ int sh[256];
  __shared__ int s_boff;
  const int t = threadIdx.x;
  const int gid = blockIdx.x * 256 + t;
  {
    int v = (t < blockIdx.x && t < 128) ? block_sums[t] : 0;
#pragma unroll
    for (int off = 32; off > 0; off >>= 1) v += __shfl_down(v, off, 64);
    if ((t & 63) == 0) sh[t >> 6] = v;
    __syncthreads();
    if (t == 0) s_boff = sh[0] + sh[1];
    __syncthreads();
  }
  int d = (gid < n) ? in_deg[gid] : 0;
  sh[t] = d;
  __syncthreads();
  for (int off = 1; off < 256; off <<= 1) {
    int v = sh[t];
    int add = (t >= off) ? sh[t - off] : 0;
    __syncthreads();
    sh[t] = v + add;
    __syncthreads();
  }
  if (gid >= n) return;
  int excl = s_boff + sh[t] - d;
  row_ptr[gid] = excl;
  if (gid == n - 1) row_ptr[n] = excl + d;
  const int w = gid >> 2;
  const int shft = (gid & 3) * 8;
  const int n4 = n >> 2;
  int cum = 0;
#pragma unroll 8
  for (int r = 0; r < NB; ++r) {
    gpre[(size_t)r * n + gid] = (uchar_t)cum;
    cum += (part_dst[(size_t)r * n4 + w] >> shft) & 0xff;
  }
}

// --- scatter: LDS rank + row_ptr + gpre; csr weight = ew * norm_src[src] ----
__global__ __launch_bounds__(1024) void scatter_kernel(const int* __restrict__ src,
                                                       const int* __restrict__ dst,
                                                       const float* __restrict__ ew,
                                                       const float* __restrict__ norm_src,
                                                       const int* __restrict__ row_ptr,
                                                       const uchar_t* __restrict__ gpre,
                                                       int2* __restrict__ csr,
                                                       int n, int e, int epb) {
  __shared__ uint32 rk[NW4];
  const int t = threadIdx.x;
  for (int w = t; w < NW4; w += 1024) rk[w] = 0;
  __syncthreads();
  const int base = blockIdx.x * epb;
  const uchar_t* gp = gpre + (size_t)blockIdx.x * n;
  for (int k = t; k < epb; k += 1024) {
    int i = base + k;
    if (i < e) {
      int s = src[i];
      int d = dst[i];
      uint32 sh = (d & 3) * 8;
      uint32 old = atomicAdd(&rk[d >> 2], 1u << sh);
      int rank = (old >> sh) & 0xff;
      int pos = row_ptr[d] + (int)gp[d] + rank;
      csr[pos] = make_int2(s, __float_as_int(ew[i] * norm_src[s]));
    }
  }
}

// ---------------------------------------------------------------------------
// MFMA GEMM, f32 input rounded to bf16-high: ht = bf16(x @ W), 2 MFMAs.
// ---------------------------------------------------------------------------
template <int K, int OUT>
__global__ __launch_bounds__(256) void gemm_mfma(const float* __restrict__ x,
                                                 const ushort_t* __restrict__ WhT,
                                                 const ushort_t* __restrict__ WlT,
                                                 ushort_t* __restrict__ ht, int n) {
  constexpr int BK = 64, KP = BK + 8;
  constexpr int NCT = OUT / 32;
  constexpr int NWLD = OUT * 16 / 256;
  __shared__ ushort_t Xh[64][KP];
  __shared__ ushort_t Wh[OUT][KP], Wl[OUT][KP];

  const int tid = threadIdx.x;
  const int wv = tid >> 6;
  const int lane = tid & 63;
  const int wr = wv >> 1;
  const int wc = wv & 1;
  const int row0 = blockIdx.x * 64;
  const int fr = lane & 15;
  const int fg = lane >> 4;

  f32x4 acc[2][NCT];
#pragma unroll
  for (int i = 0; i < 2; ++i)
#pragma unroll
    for (int j = 0; j < NCT; ++j) acc[i][j] = (f32x4){0.f, 0.f, 0.f, 0.f};

  float4 xr[4];
  ushort4 wrh[NWLD], wrl[NWLD];

#define LOADX(kg)                                                                       \
  {                                                                                     \
    _Pragma("unroll") for (int p_ = 0; p_ < 4; ++p_) {                                  \
      int idx_ = p_ * 256 + tid;                                                        \
      xr[p_] = *reinterpret_cast<const float4*>(                                        \
          x + (size_t)(row0 + (idx_ >> 4)) * K + (kg) + (idx_ & 15) * 4);               \
    }                                                                                   \
  }
#define LOADW(kg)                                                                       \
  {                                                                                     \
    _Pragma("unroll") for (int p_ = 0; p_ < NWLD; ++p_) {                               \
      int idx_ = p_ * 256 + tid;                                                        \
      int c_ = idx_ >> 4, k4_ = idx_ & 15;                                              \
      wrh[p_] = *reinterpret_cast<const ushort4*>(WhT + (size_t)c_ * K + (kg) + k4_ * 4);\
      wrl[p_] = *reinterpret_cast<const ushort4*>(WlT + (size_t)c_ * K + (kg) + k4_ * 4);\
    }                                                                                   \
  }

  LOADX(0);
  LOADW(0);

#pragma unroll 1
  for (int k0 = 0; k0 < K; k0 += BK) {
    __syncthreads();
#pragma unroll
    for (int p = 0; p < 4; ++p) {
      int idx = p * 256 + tid;
      int r = idx >> 4, c4 = idx & 15;
      float4 v = xr[p];
      ushort4 h;
      h.x = f2bf(v.x);
      h.y = f2bf(v.y);
      h.z = f2bf(v.z);
      h.w = f2bf(v.w);
      *reinterpret_cast<ushort4*>(&Xh[r][c4 * 4]) = h;
    }
#pragma unroll
    for (int p = 0; p < NWLD; ++p) {
      int idx = p * 256 + tid;
      int c = idx >> 4, k4 = idx & 15;
      *reinterpret_cast<ushort4*>(&Wh[c][k4 * 4]) = wrh[p];
      *reinterpret_cast<ushort4*>(&Wl[c][k4 * 4]) = wrl[p];
    }
    if (k0 + BK < K) {
      LOADX(k0 + BK);
      LOADW(k0 + BK);
    }
    __syncthreads();

#pragma unroll
    for (int s = 0; s < 2; ++s) {
      const int kk = s * 32 + fg * 8;
      bf16x8 ah[2];
#pragma unroll
      for (int i = 0; i < 2; ++i)
        ah[i] = *reinterpret_cast<const bf16x8*>(&Xh[wr * 32 + i * 16 + fr][kk]);
#pragma unroll
      for (int j = 0; j < NCT; ++j) {
        int c = wc * (OUT / 2) + j * 16 + fr;
        bf16x8 bh = *reinterpret_cast<const bf16x8*>(&Wh[c][kk]);
        bf16x8 bl = *reinterpret_cast<const bf16x8*>(&Wl[c][kk]);
#pragma unroll
        for (int i = 0; i < 2; ++i) {
          acc[i][j] = __builtin_amdgcn_mfma_f32_16x16x32_bf16(ah[i], bh, acc[i][j], 0, 0, 0);
          acc[i][j] = __builtin_amdgcn_mfma_f32_16x16x32_bf16(ah[i], bl, acc[i][j], 0, 0, 0);
        }
      }
    }
  }
#undef LOADX
#undef LOADW

#pragma unroll
  for (int i = 0; i < 2; ++i) {
#pragma unroll
    for (int q = 0; q < 4; ++q) {
      int row = row0 + wr * 32 + i * 16 + fg * 4 + q;
#pragma unroll
      for (int j = 0; j < NCT; ++j) {
        int col = wc * (OUT / 2) + j * 16 + fr;
        ht[(size_t)row * OUT + col] = f2bf(acc[i][j][q]);
      }
    }
  }
}

// ---------------------------------------------------------------------------
// bf16-input MFMA GEMM, W bf16-high only: 1 MFMA per fragment.
// ---------------------------------------------------------------------------
template <int K, int OUT>
__global__ __launch_bounds__(256) void gemm_mfma_bf16in(const ushort_t* __restrict__ x,
                                                        const ushort_t* __restrict__ WhT,
                                                        ushort_t* __restrict__ ht, int n) {
  constexpr int BK = 64, KP = BK + 8;
  constexpr int NCT = OUT / 32;
  constexpr int NWLD = OUT * 16 / 256;
  __shared__ ushort_t Xh[64][KP];
  __shared__ ushort_t Wh[OUT][KP];

  const int tid = threadIdx.x;
  const int wv = tid >> 6;
  const int lane = tid & 63;
  const int wr = wv >> 1;
  const int wc = wv & 1;
  const int row0 = blockIdx.x * 64;
  const int fr = lane & 15;
  const int fg = lane >> 4;

  f32x4 acc[2][NCT];
#pragma unroll
  for (int i = 0; i < 2; ++i)
#pragma unroll
    for (int j = 0; j < NCT; ++j) acc[i][j] = (f32x4){0.f, 0.f, 0.f, 0.f};

  ushort4 xr[4];
  ushort4 wrh[NWLD];

#define LOADX(kg)                                                                       \
  {                                                                                     \
    _Pragma("unroll") for (int p_ = 0; p_ < 4; ++p_) {                                  \
      int idx_ = p_ * 256 + tid;                                                        \
      xr[p_] = *reinterpret_cast<const ushort4*>(                                       \
          x + (size_t)(row0 + (idx_ >> 4)) * K + (kg) + (idx_ & 15) * 4);               \
    }                                                                                   \
  }
#define LOADW(kg)                                                                       \
  {                                                                                     \
    _Pragma("unroll") for (int p_ = 0; p_ < NWLD; ++p_) {                               \
      int idx_ = p_ * 256 + tid;                                                        \
      int c_ = idx_ >> 4, k4_ = idx_ & 15;                                              \
      wrh[p_] = *reinterpret_cast<const ushort4*>(WhT + (size_t)c_ * K + (kg) + k4_ * 4);\
    }                                                                                   \
  }

  LOADX(0);
  LOADW(0);

#pragma unroll 1
  for (int k0 = 0; k0 < K; k0 += BK) {
    __syncthreads();
#pragma unroll
    for (int p = 0; p < 4; ++p) {
      int idx = p * 256 + tid;
      *reinterpret_cast<ushort4*>(&Xh[idx >> 4][(idx & 15) * 4]) = xr[p];
    }
#pragma unroll
    for (int p = 0; p < NWLD; ++p) {
      int idx = p * 256 + tid;
      *reinterpret_cast<ushort4*>(&Wh[idx >> 4][(idx & 15) * 4]) = wrh[p];
    }
    if (k0 + BK < K) {
      LOADX(k0 + BK);
      LOADW(k0 + BK);
    }
    __syncthreads();

#pragma unroll
    for (int s = 0; s < 2; ++s) {
      const int kk = s * 32 + fg * 8;
      bf16x8 ah[2];
#pragma unroll
      for (int i = 0; i < 2; ++i)
        ah[i] = *reinterpret_cast<const bf16x8*>(&Xh[wr * 32 + i * 16 + fr][kk]);
#pragma unroll
      for (int j = 0; j < NCT; ++j) {
        int c = wc * (OUT / 2) + j * 16 + fr;
        bf16x8 bh = *reinterpret_cast<const bf16x8*>(&Wh[c][kk]);
#pragma unroll
        for (int i = 0; i < 2; ++i)
          acc[i][j] = __builtin_amdgcn_mfma_f32_16x16x32_bf16(ah[i], bh, acc[i][j], 0, 0, 0);
      }
    }
  }
#undef LOADX
#undef LOADW

#pragma unroll
  for (int i = 0; i < 2; ++i) {
#pragma unroll
    for (int q = 0; q < 4; ++q) {
      int row = row0 + wr * 32 + i * 16 + fg * 4 + q;
#pragma unroll
      for (int j = 0; j < NCT; ++j) {
        int col = wc * (OUT / 2) + j * 16 + fr;
        ht[(size_t)row * OUT + col] = f2bf(acc[i][j][q]);
      }
    }
  }
}

// bf16 gather: 4 bf16 (8B) per lane-group slot
#define GATHB(e, acc)                                                               \
  {                                                                                 \
    float w_ = __int_as_float(e.y);                                                 \
    ushort4 h_ = *reinterpret_cast<const ushort4*>(ht + (size_t)e.x * OUT + cg * 4);\
    acc.x += w_ * bf2f(h_.x);                                                       \
    acc.y += w_ * bf2f(h_.y);                                                       \
    acc.z += w_ * bf2f(h_.z);                                                       \
    acc.w += w_ * bf2f(h_.w);                                                       \
  }

// out[v] = tanh(nd*sum + b), written bf16
template <int OUT>
__global__ void aggregate_kernel(const ushort_t* __restrict__ ht, const int* __restrict__ row_ptr,
                                 const int2* __restrict__ csr, const float* __restrict__ norm_dst,
                                 const float* __restrict__ bias, ushort_t* __restrict__ out,
                                 int n) {
  constexpr int LPN = OUT / 4;
  constexpr int NPB = 256 / LPN;
  const int tid = threadIdx.x;
  const int cg = tid % LPN;
  const int v = blockIdx.x * NPB + tid / LPN;
  if (v >= n) return;

  const int s0 = row_ptr[v];
  const int s1 = row_ptr[v + 1];
  float4 a0 = {0, 0, 0, 0}, a1 = {0, 0, 0, 0}, a2 = {0, 0, 0, 0}, a3 = {0, 0, 0, 0};
  int i = s0;
  for (; i + 4 <= s1; i += 4) {
    int2 e0 = csr[i], e1 = csr[i + 1], e2 = csr[i + 2], e3 = csr[i + 3];
    GATHB(e0, a0);
    GATHB(e1, a1);
    GATHB(e2, a2);
    GATHB(e3, a3);
  }
  for (; i < s1; ++i) {
    int2 e = csr[i];
    GATHB(e, a0);
  }
  float nd = norm_dst[v];
  float4 b4 = *reinterpret_cast<const float4*>(bias + cg * 4);
  ushort4 r;
  r.x = f2bf(fast_tanh((a0.x + a1.x + a2.x + a3.x) * nd + b4.x));
  r.y = f2bf(fast_tanh((a0.y + a1.y + a2.y + a3.y) * nd + b4.y));
  r.z = f2bf(fast_tanh((a0.z + a1.z + a2.z + a3.z) * nd + b4.z));
  r.w = f2bf(fast_tanh((a0.w + a1.w + a2.w + a3.w) * nd + b4.w));
  *reinterpret_cast<ushort4*>(out + (size_t)v * OUT + cg * 4) = r;
}

// Layer-2 aggregate fused with layer-3 transform (norm folded into csr_w).
__global__ void aggregate2_fuse3(const ushort_t* __restrict__ ht, const int* __restrict__ row_ptr,
                                 const int2* __restrict__ csr, const float* __restrict__ norm_dst,
                                 const float* __restrict__ bias, const float* __restrict__ W3,
                                 float* __restrict__ ht3, int n) {
  constexpr int OUT = 64;
  constexpr int LPN = OUT / 4; // 16
  constexpr int NPB = 256 / LPN;
  const int tid = threadIdx.x;
  const int cg = tid % LPN;
  const int v = blockIdx.x * NPB + tid / LPN;
  if (v >= n) return;

  const int s0 = row_ptr[v];
  const int s1 = row_ptr[v + 1];
  float4 a0 = {0, 0, 0, 0}, a1 = {0, 0, 0, 0}, a2 = {0, 0, 0, 0}, a3 = {0, 0, 0, 0};
  int i = s0;
  for (; i + 4 <= s1; i += 4) {
    int2 e0 = csr[i], e1 = csr[i + 1], e2 = csr[i + 2], e3 = csr[i + 3];
    GATHB(e0, a0);
    GATHB(e1, a1);
    GATHB(e2, a2);
    GATHB(e3, a3);
  }
  for (; i < s1; ++i) {
    int2 e = csr[i];
    GATHB(e, a0);
  }
  float nd = norm_dst[v];
  float4 b4 = *reinterpret_cast<const float4*>(bias + cg * 4);
  float ox = fast_tanh((a0.x + a1.x + a2.x + a3.x) * nd + b4.x);
  float oy = fast_tanh((a0.y + a1.y + a2.y + a3.y) * nd + b4.y);
  float oz = fast_tanh((a0.z + a1.z + a2.z + a3.z) * nd + b4.z);
  float ow = fast_tanh((a0.w + a1.w + a2.w + a3.w) * nd + b4.w);
  float4 w3 = *reinterpret_cast<const float4*>(W3 + cg * 4);
  float p = ox * w3.x + oy * w3.y + oz * w3.z + ow * w3.w;
#pragma unroll
  for (int m = 1; m < 16; m <<= 1) p += __shfl_xor(p, m, 64);
  if (cg == 0) ht3[v] = p;
}

__global__ void aggregate3_kernel(const float* __restrict__ ht3, const int* __restrict__ row_ptr,
                                  const int2* __restrict__ csr, const float* __restrict__ norm_dst,
                                  const float* __restrict__ b3, float* __restrict__ out, int n) {
  int v = blockIdx.x * blockDim.x + threadIdx.x;
  if (v >= n) return;
  const int s0 = row_ptr[v];
  const int s1 = row_ptr[v + 1];
  float p0 = 0.f, p1 = 0.f, p2 = 0.f, p3 = 0.f;
  int i = s0;
  for (; i + 4 <= s1; i += 4) {
    int2 e0 = csr[i], e1 = csr[i + 1], e2 = csr[i + 2], e3 = csr[i + 3];
    p0 += __int_as_float(e0.y) * ht3[e0.x];
    p1 += __int_as_float(e1.y) * ht3[e1.x];
    p2 += __int_as_float(e2.y) * ht3[e2.x];
    p3 += __int_as_float(e3.y) * ht3[e3.x];
  }
  for (; i < s1; ++i) {
    int2 e = csr[i];
    p0 += __int_as_float(e.y) * ht3[e.x];
  }
  out[v] = (p0 + p1 + p2 + p3) * norm_dst[v] + b3[0];
}

extern "C" void kernel_launch(void* const* d_in, const int* in_sizes, int n_in,
                              void* d_out, int out_size, void* d_ws, size_t ws_size,
                              hipStream_t stream) {
  const float* b_z = (const float*)d_in[0];
  const int* src = (const int*)d_in[1];
  const int* dst = (const int*)d_in[2];
  const float* ew = (const float*)d_in[3];
  const float* W1 = (const float*)d_in[4];
  const float* b1 = (const float*)d_in[5];
  const float* W2 = (const float*)d_in[6];
  const float* b2 = (const float*)d_in[7];
  const float* W3 = (const float*)d_in[8];
  const float* b3 = (const float*)d_in[9];

  const int N = in_sizes[0] / 256; // 32768
  const int E = in_sizes[1];       // 524288
  const int N4 = N / 4;            // 8192
  const int epb = (E + NB - 1) / NB; // 2048

  char* ws = (char*)d_ws;
  size_t off = 0;
  auto alloc = [&](size_t bytes) -> void* {
    void* p = ws + off;
    off += (bytes + 255) & ~(size_t)255;
    return p;
  };

  uint32* part = (uint32*)alloc((size_t)2 * NB * N4 * 4); // 16 MB
  uchar_t* gpre = (uchar_t*)alloc((size_t)NB * N);        // 8 MB
  float* norm_src = (float*)alloc((size_t)N * 4);
  float* norm_dst = (float*)alloc((size_t)N * 4);
  int* in_deg = (int*)alloc((size_t)N * 4);
  int* row_ptr = (int*)alloc((size_t)(N + 1) * 4);
  int* block_sums = (int*)alloc(256 * 4);
  int2* csr = (int2*)alloc((size_t)E * 8);
  ushort_t* HT = (ushort_t*)alloc((size_t)N * 128 * 2);   // bf16 ht1 / ht2 (reused)
  ushort_t* ACT1 = (ushort_t*)alloc((size_t)N * 128 * 2); // bf16 layer1 activation
  float* HT3 = (float*)alloc((size_t)N * 4);
  ushort_t* WhT1 = (ushort_t*)alloc((size_t)256 * 128 * 2);
  ushort_t* WlT1 = (ushort_t*)alloc((size_t)256 * 128 * 2);
  ushort_t* WhT2 = (ushort_t*)alloc((size_t)128 * 64 * 2);

  const uint32* part_dst = part + (size_t)NB * N4;
  const int nBlocks = (N + 255) / 256; // 128
  const int wsBlocks = (256 * 128 + 128 * 64 + 1023) / 1024; // 40

  hist_wsplit_kernel<<<NB + wsBlocks, 1024, 0, stream>>>(src, dst, part, W1, W2, WhT1, WlT1,
                                                         WhT2, E, epb);
  norm_reduce<<<64, 1024, 0, stream>>>(part, norm_src, norm_dst, in_deg, block_sums, N4);
  scan_write_goffs<<<nBlocks, 256, 0, stream>>>(in_deg, block_sums, part_dst, row_ptr, gpre, N);
  scatter_kernel<<<NB, 1024, 0, stream>>>(src, dst, ew, norm_src, row_ptr, gpre, csr, N, E, epb);

  // Layer 1: 256 -> 128, tanh (output bf16)
  gemm_mfma<256, 128><<<N / 64, 256, 0, stream>>>(b_z, WhT1, WlT1, HT, N);
  aggregate_kernel<128><<<(N + 7) / 8, 256, 0, stream>>>(HT, row_ptr, csr, norm_dst, b1, ACT1, N);
  // Layer 2: 128 -> 64 (tanh) fused with layer-3 transform (64 -> 1)
  gemm_mfma_bf16in<128, 64><<<N / 64, 256, 0, stream>>>(ACT1, WhT2, HT, N);
  aggregate2_fuse3<<<(N + 15) / 16, 256, 0, stream>>>(HT, row_ptr, csr, norm_dst, b2, W3, HT3, N);
  // Layer 3 aggregate: 1 col, no tanh
  aggregate3_kernel<<<nBlocks, 256, 0, stream>>>(HT3, row_ptr, csr, norm_dst, b3,
                                                 (float*)d_out, N);
}